// Round 2
// baseline (281.450 us; speedup 1.0000x reference)
//
#include <hip/hip_runtime.h>
#include <hip/hip_bf16.h>

// MHA forward, MI355X/gfx950.
// Pipeline: cast->bf16 (2 launches), fused QKV proj (one MFMA NT-GEMM, N=3072),
// causal flash attention, out proj.

#define DEVI __device__ __forceinline__

typedef __attribute__((ext_vector_type(4))) float f32x4;
typedef __attribute__((ext_vector_type(8))) short s16x8;

static constexpr int SEQ = 2048;
static constexpr int DM  = 1024;
static constexpr int NH  = 16;
static constexpr int HD  = 64;
static constexpr int LDQKV = 3072;   // fused QKV row stride

DEVI short f2bf(float f) {
  __hip_bfloat16 h = __float2bfloat16(f);
  return *(short*)&h;
}

// ---------------- fp32 -> bf16 casts ----------------
__global__ void cast_kernel(const float* __restrict__ in, short* __restrict__ out, int n4) {
  int i = blockIdx.x * blockDim.x + threadIdx.x;
  if (i >= n4) return;
  float4 v = ((const float4*)in)[i];
  short4 o;
  o.x = f2bf(v.x); o.y = f2bf(v.y); o.z = f2bf(v.z); o.w = f2bf(v.w);
  ((short4*)out)[i] = o;
}

// 4 weight matrices, 1M floats (256K float4) each. seg = blockIdx>>10.
__global__ void cast4_kernel(const float* __restrict__ w0, const float* __restrict__ w1,
                             const float* __restrict__ w2, const float* __restrict__ w3,
                             short* __restrict__ o012, short* __restrict__ o3) {
  int seg = blockIdx.x >> 10;
  int i = (blockIdx.x & 1023) * blockDim.x + threadIdx.x;   // 0..256K-1 (float4 idx)
  const float* src = (seg == 0) ? w0 : (seg == 1) ? w1 : (seg == 2) ? w2 : w3;
  short* dst = (seg == 3) ? o3 : (o012 + (size_t)seg * (1u << 20));
  float4 v = ((const float4*)src)[i];
  short4 o;
  o.x = f2bf(v.x); o.y = f2bf(v.y); o.z = f2bf(v.z); o.w = f2bf(v.w);
  ((short4*)dst)[i] = o;
}

// ---------------- NT GEMM: C[m][n] = sum_k A[m][k]*B[n][k] ----------------
// A: M x K bf16 row-major, B: N x K bf16 row-major. 128x128 tile, BK=32,
// 4 waves each computing a 64x64 quadrant (4x4 frags of 16x16x32 MFMA).
// m97 structure: global_load_lds width-16 staging, 2 barriers/K-step.
template<bool BF16_OUT>
__global__ __launch_bounds__(256) void gemm_nt(const short* __restrict__ A,
                                               const short* __restrict__ Bm,
                                               void* __restrict__ Cv,
                                               int M, int N, int K) {
  __shared__ short As[128 * 32];
  __shared__ short Bs[128 * 32];
  const int t = threadIdx.x;
  const int l = t & 63;
  const int w = t >> 6;
  const int wr = w >> 1, wc = w & 1;
  const int lr = l & 15, lg = l >> 4;
  const int m0 = blockIdx.y * 128, n0 = blockIdx.x * 128;
  f32x4 acc[4][4] = {};

  for (int k0 = 0; k0 < K; k0 += 32) {
    __syncthreads();  // previous iteration's LDS reads done
#pragma unroll
    for (int i = 0; i < 2; ++i) {
      int idx = t * 8 + i * 2048;     // flat bf16 element index into 128x32 tile
      int row = idx >> 5, col = idx & 31;
      __builtin_amdgcn_global_load_lds(
          (const __attribute__((address_space(1))) void*)(A + (size_t)(m0 + row) * K + k0 + col),
          (__attribute__((address_space(3))) void*)(As + idx), 16, 0, 0);
      __builtin_amdgcn_global_load_lds(
          (const __attribute__((address_space(1))) void*)(Bm + (size_t)(n0 + row) * K + k0 + col),
          (__attribute__((address_space(3))) void*)(Bs + idx), 16, 0, 0);
    }
    __syncthreads();  // staged (compiler drains vmcnt before barrier)

    s16x8 af[4], bfr[4];
#pragma unroll
    for (int i = 0; i < 4; ++i)
      af[i] = *(const s16x8*)&As[(wr * 64 + i * 16 + lr) * 32 + lg * 8];
#pragma unroll
    for (int j = 0; j < 4; ++j)
      bfr[j] = *(const s16x8*)&Bs[(wc * 64 + j * 16 + lr) * 32 + lg * 8];
#pragma unroll
    for (int i = 0; i < 4; ++i)
#pragma unroll
      for (int j = 0; j < 4; ++j)
        acc[i][j] = __builtin_amdgcn_mfma_f32_16x16x32_bf16(af[i], bfr[j], acc[i][j], 0, 0, 0);
  }

  // epilogue: D[row=(l>>4)*4+r][col=l&15] per frag
#pragma unroll
  for (int i = 0; i < 4; ++i)
#pragma unroll
    for (int j = 0; j < 4; ++j)
#pragma unroll
      for (int r = 0; r < 4; ++r) {
        int row = m0 + wr * 64 + i * 16 + lg * 4 + r;
        int col = n0 + wc * 64 + j * 16 + lr;
        if constexpr (BF16_OUT)
          ((short*)Cv)[(size_t)row * N + col] = f2bf(acc[i][j][r]);
        else
          ((float*)Cv)[(size_t)row * N + col] = acc[i][j][r];
      }
}

// ---------------- causal flash attention ----------------
// QKV: [B*S, 3072] bf16 (row = b*SEQ + s; Q at col h*64, K at 1024+h*64, V at 2048+h*64).
// O: [B*S, 1024] bf16. Block: 64 q-rows of one (b,h). 4 waves x 16 q-rows. KV tiles of 64.
// LDS rows padded to 72 elems (144B: 16B-aligned, conflict-spreading).
__global__ __launch_bounds__(256) void attn_kernel(const unsigned short* __restrict__ QKV,
                                                   unsigned short* __restrict__ O) {
  __shared__ short Ks[64 * 72];
  __shared__ short Vt[64 * 72];   // transposed: Vt[d][kv]
  __shared__ short Ps[64 * 72];

  const int t = threadIdx.x, l = t & 63, w = t >> 6;
  const int lr = l & 15, lg = l >> 4;
  const int qt = blockIdx.x;            // q-tile 0..31
  const int bh = blockIdx.y;            // b*NH + h
  const int b = bh >> 4, h = bh & 15;
  const int q0 = qt * 64;
  const size_t rowbase = (size_t)b * SEQ * LDQKV;
  const int cb = h * HD;
  const unsigned short* Q = QKV + cb;
  const unsigned short* K = QKV + DM + cb;
  const unsigned short* V = QKV + 2 * DM + cb;

  // Q fragments in registers: rows q0 + w*16 + lr, k-slices lg*8 (+32)
  s16x8 qf[2];
  {
    const unsigned short* qp = Q + rowbase + (size_t)(q0 + w * 16 + lr) * LDQKV + lg * 8;
    qf[0] = *(const s16x8*)(qp);
    qf[1] = *(const s16x8*)(qp + 32);
  }

  f32x4 acc[4] = {};
  float mrun[4], lrun[4];
#pragma unroll
  for (int r = 0; r < 4; ++r) { mrun[r] = -3.0e38f; lrun[r] = 0.f; }

  // logits kept in base-2 domain: scale = 1/sqrt(64) * log2(e)
  const float SCL = 0.125f * 1.4426950408889634f;

  for (int kt = 0; kt <= qt; ++kt) {
    const int kv0 = kt * 64;
    __syncthreads();  // previous PV reads of Ks/Vt done
    // ---- stage K tile + transposed V tile: thread covers kv=l, d-slice w*16..+15
    {
      const unsigned short* kp = K + rowbase + (size_t)(kv0 + l) * LDQKV + w * 16;
      s16x8 k0v = *(const s16x8*)kp;
      s16x8 k1v = *(const s16x8*)(kp + 8);
      *(s16x8*)&Ks[l * 72 + w * 16] = k0v;
      *(s16x8*)&Ks[l * 72 + w * 16 + 8] = k1v;
      const unsigned short* vp = V + rowbase + (size_t)(kv0 + l) * LDQKV + w * 16;
      s16x8 v0v = *(const s16x8*)vp;
      s16x8 v1v = *(const s16x8*)(vp + 8);
#pragma unroll
      for (int jj = 0; jj < 8; ++jj) Vt[(w * 16 + jj) * 72 + l] = v0v[jj];
#pragma unroll
      for (int jj = 0; jj < 8; ++jj) Vt[(w * 16 + 8 + jj) * 72 + l] = v1v[jj];
    }
    __syncthreads();

    // ---- S = Q K^T  (frag j covers kv cols j*16..; dk covers d 32-chunks)
    f32x4 sc[4] = {};
    __builtin_amdgcn_s_setprio(1);
#pragma unroll
    for (int dk = 0; dk < 2; ++dk)
#pragma unroll
      for (int j = 0; j < 4; ++j) {
        s16x8 kb = *(const s16x8*)&Ks[(j * 16 + lr) * 72 + dk * 32 + lg * 8];
        sc[j] = __builtin_amdgcn_mfma_f32_16x16x32_bf16(qf[dk], kb, sc[j], 0, 0, 0);
      }
    __builtin_amdgcn_s_setprio(0);

    // ---- scale (base-2 domain) + causal mask
#pragma unroll
    for (int j = 0; j < 4; ++j)
#pragma unroll
      for (int r = 0; r < 4; ++r) {
        float v = sc[j][r] * SCL;
        int kg = kv0 + j * 16 + lr;
        int qg = q0 + w * 16 + lg * 4 + r;
        sc[j][r] = (kg > qg) ? -3.0e38f : v;
      }

    // ---- online softmax per row r (row lives in 16 lanes sharing lg)
#pragma unroll
    for (int r = 0; r < 4; ++r) {
      float rmax = fmaxf(fmaxf(sc[0][r], sc[1][r]), fmaxf(sc[2][r], sc[3][r]));
#pragma unroll
      for (int mk = 1; mk < 16; mk <<= 1) rmax = fmaxf(rmax, __shfl_xor(rmax, mk, 64));
      float mnew = fmaxf(mrun[r], rmax);
      float corr = exp2f(mrun[r] - mnew);
      mrun[r] = mnew;
      float rsum = 0.f;
#pragma unroll
      for (int j = 0; j < 4; ++j) {
        float p = exp2f(sc[j][r] - mnew);
        sc[j][r] = p;
        rsum += p;
      }
#pragma unroll
      for (int mk = 1; mk < 16; mk <<= 1) rsum += __shfl_xor(rsum, mk, 64);
      lrun[r] = lrun[r] * corr + rsum;
#pragma unroll
      for (int j = 0; j < 4; ++j) acc[j][r] *= corr;
    }

    // ---- P -> LDS (D-layout -> A-layout transpose through LDS)
#pragma unroll
    for (int j = 0; j < 4; ++j)
#pragma unroll
      for (int r = 0; r < 4; ++r)
        Ps[(w * 16 + lg * 4 + r) * 72 + j * 16 + lr] = f2bf(sc[j][r]);
    __syncthreads();

    // ---- O += P @ V
    __builtin_amdgcn_s_setprio(1);
#pragma unroll
    for (int ks = 0; ks < 2; ++ks) {
      s16x8 pa = *(const s16x8*)&Ps[(w * 16 + lr) * 72 + ks * 32 + lg * 8];
#pragma unroll
      for (int j = 0; j < 4; ++j) {
        s16x8 vb = *(const s16x8*)&Vt[(j * 16 + lr) * 72 + ks * 32 + lg * 8];
        acc[j] = __builtin_amdgcn_mfma_f32_16x16x32_bf16(pa, vb, acc[j], 0, 0, 0);
      }
    }
    __builtin_amdgcn_s_setprio(0);
  }

  // ---- epilogue: O[q][d] = acc/lsum
#pragma unroll
  for (int j = 0; j < 4; ++j)
#pragma unroll
    for (int r = 0; r < 4; ++r) {
      int qg = q0 + w * 16 + lg * 4 + r;
      float o = acc[j][r] / lrun[r];
      O[(size_t)b * SEQ * DM + (size_t)qg * DM + cb + j * 16 + lr] = (unsigned short)f2bf(o);
    }
}

// ---------------- launch ----------------
extern "C" void kernel_launch(void* const* d_in, const int* in_sizes, int n_in,
                              void* d_out, int out_size, void* d_ws, size_t ws_size,
                              hipStream_t stream) {
  const float* x  = (const float*)d_in[0];
  const float* wq = (const float*)d_in[1];
  const float* wk = (const float*)d_in[2];
  const float* wv = (const float*)d_in[3];
  const float* wo = (const float*)d_in[4];
  float* out = (float*)d_out;

  short* ws   = (short*)d_ws;
  short* xb   = ws;                     // 4M elems  [4096,1024]
  short* wqkv = xb   + (4u << 20);      // 3M elems  [3072,1024] (wq;wk;wv)
  short* wob  = wqkv + (3u << 20);      // 1M elems  [1024,1024]
  short* QKV  = wob  + (1u << 20);      // 12M elems [4096,3072]
  short* Om   = QKV  + (12u << 20);     // 4M elems  [4096,1024]
  // total 24M shorts = 48 MB

  cast_kernel<<<4096, 256, 0, stream>>>(x, xb, 1 << 20);
  cast4_kernel<<<4096, 256, 0, stream>>>(wq, wk, wv, wo, wqkv, wob);

  // fused QKV projection: [4096,1024] x [3072,1024]^T -> [4096,3072]
  gemm_nt<true><<<dim3(24, 32), 256, 0, stream>>>(xb, wqkv, QKV, 4096, LDQKV, 1024);

  attn_kernel<<<dim3(32, 32), 256, 0, stream>>>((const unsigned short*)QKV,
                                                (unsigned short*)Om);

  // output projection: [4096,1024] x [1024,1024]^T -> [4096,1024] fp32
  gemm_nt<false><<<dim3(8, 32), 256, 0, stream>>>(Om, wob, out, 4096, 1024, 1024);
}

// Round 4
// 224.437 us; speedup vs baseline: 1.2540x; 1.2540x over previous
//
#include <hip/hip_runtime.h>
#include <hip/hip_bf16.h>

// MHA forward, MI355X/gfx950.
// Pipeline: cast->bf16 (2 launches), fused QKV proj (one MFMA NT-GEMM, N=3072),
// causal flash attention (exact-balance 1D grid), out proj.

#define DEVI __device__ __forceinline__

typedef __attribute__((ext_vector_type(4))) float f32x4;
typedef __attribute__((ext_vector_type(8))) short s16x8;

static constexpr int SEQ = 2048;
static constexpr int DM  = 1024;
static constexpr int NH  = 16;
static constexpr int HD  = 64;
static constexpr int LDQKV = 3072;   // fused QKV row stride

DEVI short f2bf(float f) {
  __hip_bfloat16 h = __float2bfloat16(f);
  return *(short*)&h;
}

// ---------------- fp32 -> bf16 casts ----------------
__global__ void cast_kernel(const float* __restrict__ in, short* __restrict__ out, int n4) {
  int i = blockIdx.x * blockDim.x + threadIdx.x;
  if (i >= n4) return;
  float4 v = ((const float4*)in)[i];
  short4 o;
  o.x = f2bf(v.x); o.y = f2bf(v.y); o.z = f2bf(v.z); o.w = f2bf(v.w);
  ((short4*)out)[i] = o;
}

// 4 weight matrices, 1M floats (256K float4) each. seg = blockIdx>>10.
__global__ void cast4_kernel(const float* __restrict__ w0, const float* __restrict__ w1,
                             const float* __restrict__ w2, const float* __restrict__ w3,
                             short* __restrict__ o012, short* __restrict__ o3) {
  int seg = blockIdx.x >> 10;
  int i = (blockIdx.x & 1023) * blockDim.x + threadIdx.x;   // 0..256K-1 (float4 idx)
  const float* src = (seg == 0) ? w0 : (seg == 1) ? w1 : (seg == 2) ? w2 : w3;
  short* dst = (seg == 3) ? o3 : (o012 + (size_t)seg * (1u << 20));
  float4 v = ((const float4*)src)[i];
  short4 o;
  o.x = f2bf(v.x); o.y = f2bf(v.y); o.z = f2bf(v.z); o.w = f2bf(v.w);
  ((short4*)dst)[i] = o;
}

// ---------------- NT GEMM: C[m][n] = sum_k A[m][k]*B[n][k] ----------------
// A: M x K bf16 row-major, B: N x K bf16 row-major. 128x128 tile, BK=32,
// 4 waves each computing a 64x64 quadrant (4x4 frags of 16x16x32 MFMA).
// m97 structure: global_load_lds width-16 staging, 2 barriers/K-step.
template<bool BF16_OUT>
__global__ __launch_bounds__(256) void gemm_nt(const short* __restrict__ A,
                                               const short* __restrict__ Bm,
                                               void* __restrict__ Cv,
                                               int M, int N, int K) {
  __shared__ short As[128 * 32];
  __shared__ short Bs[128 * 32];
  const int t = threadIdx.x;
  const int l = t & 63;
  const int w = t >> 6;
  const int wr = w >> 1, wc = w & 1;
  const int lr = l & 15, lg = l >> 4;
  const int m0 = blockIdx.y * 128, n0 = blockIdx.x * 128;
  f32x4 acc[4][4] = {};

  for (int k0 = 0; k0 < K; k0 += 32) {
    __syncthreads();  // previous iteration's LDS reads done
#pragma unroll
    for (int i = 0; i < 2; ++i) {
      int idx = t * 8 + i * 2048;     // flat bf16 element index into 128x32 tile
      int row = idx >> 5, col = idx & 31;
      __builtin_amdgcn_global_load_lds(
          (const __attribute__((address_space(1))) void*)(A + (size_t)(m0 + row) * K + k0 + col),
          (__attribute__((address_space(3))) void*)(As + idx), 16, 0, 0);
      __builtin_amdgcn_global_load_lds(
          (const __attribute__((address_space(1))) void*)(Bm + (size_t)(n0 + row) * K + k0 + col),
          (__attribute__((address_space(3))) void*)(Bs + idx), 16, 0, 0);
    }
    __syncthreads();  // staged (compiler drains vmcnt before barrier)

    s16x8 af[4], bfr[4];
#pragma unroll
    for (int i = 0; i < 4; ++i)
      af[i] = *(const s16x8*)&As[(wr * 64 + i * 16 + lr) * 32 + lg * 8];
#pragma unroll
    for (int j = 0; j < 4; ++j)
      bfr[j] = *(const s16x8*)&Bs[(wc * 64 + j * 16 + lr) * 32 + lg * 8];
#pragma unroll
    for (int i = 0; i < 4; ++i)
#pragma unroll
      for (int j = 0; j < 4; ++j)
        acc[i][j] = __builtin_amdgcn_mfma_f32_16x16x32_bf16(af[i], bfr[j], acc[i][j], 0, 0, 0);
  }

  // epilogue: D[row=(l>>4)*4+r][col=l&15] per frag
#pragma unroll
  for (int i = 0; i < 4; ++i)
#pragma unroll
    for (int j = 0; j < 4; ++j)
#pragma unroll
      for (int r = 0; r < 4; ++r) {
        int row = m0 + wr * 64 + i * 16 + lg * 4 + r;
        int col = n0 + wc * 64 + j * 16 + lr;
        if constexpr (BF16_OUT)
          ((short*)Cv)[(size_t)row * N + col] = f2bf(acc[i][j][r]);
        else
          ((float*)Cv)[(size_t)row * N + col] = acc[i][j][r];
      }
}

// ---------------- causal flash attention ----------------
// QKV: [B*S, 3072] bf16 (row = b*SEQ + s; Q at col h*64, K at 1024+h*64, V at 2048+h*64).
// O: [B*S, 1024] bf16.
// Exact-balance 1D grid (1024 blocks): bid -> bh = bid&31 (fast), g = (bid>>5)&7,
// r = bid>>8; qt = {g, 31-g, 8+g, 23-g}[r]. Any dispatch that co-locates
// {bid, bid+256, bid+512, bid+768} on one CU gives every CU exactly
// (g+1)+(32-g)+(g+9)+(24-g) = 66 kv-tile units -> no causal tail. (bh,qt) stays
// a bijection, so correctness is mapping-independent.
// Block: 64 q-rows of one (b,h). 4 waves x 16 q-rows. KV tiles of 64.
// LDS rows padded to 72 elems (144B: 16B-aligned, conflict-spreading).
__global__ __launch_bounds__(256) void attn_kernel(const unsigned short* __restrict__ QKV,
                                                   unsigned short* __restrict__ O) {
  __shared__ short Ks[64 * 72];
  __shared__ short Vt[64 * 72];   // transposed: Vt[d][kv]
  __shared__ short Ps[64 * 72];

  const int t = threadIdx.x, l = t & 63, w = t >> 6;
  const int lr = l & 15, lg = l >> 4;
  const int bid = blockIdx.x;
  const int bh = bid & 31;              // fast dim: b*NH+h
  const int g  = (bid >> 5) & 7;
  const int rr = bid >> 8;
  const int qt = (rr == 0) ? g : (rr == 1) ? 31 - g : (rr == 2) ? 8 + g : 23 - g;
  const int b = bh >> 4, h = bh & 15;
  const int q0 = qt * 64;
  const size_t rowbase = (size_t)b * SEQ * LDQKV;
  const int cb = h * HD;
  const unsigned short* Q = QKV + cb;
  const unsigned short* K = QKV + DM + cb;
  const unsigned short* V = QKV + 2 * DM + cb;

  // Q fragments in registers: rows q0 + w*16 + lr, k-slices lg*8 (+32)
  s16x8 qf[2];
  {
    const unsigned short* qp = Q + rowbase + (size_t)(q0 + w * 16 + lr) * LDQKV + lg * 8;
    qf[0] = *(const s16x8*)(qp);
    qf[1] = *(const s16x8*)(qp + 32);
  }

  f32x4 acc[4] = {};
  float mrun[4], lrun[4];
#pragma unroll
  for (int r = 0; r < 4; ++r) { mrun[r] = -3.0e38f; lrun[r] = 0.f; }

  // logits kept in base-2 domain: scale = 1/sqrt(64) * log2(e)
  const float SCL = 0.125f * 1.4426950408889634f;

  for (int kt = 0; kt <= qt; ++kt) {
    const int kv0 = kt * 64;
    __syncthreads();  // previous PV reads of Ks/Vt done
    // ---- stage K tile + transposed V tile: thread covers kv=l, d-slice w*16..+15
    {
      const unsigned short* kp = K + rowbase + (size_t)(kv0 + l) * LDQKV + w * 16;
      s16x8 k0v = *(const s16x8*)kp;
      s16x8 k1v = *(const s16x8*)(kp + 8);
      *(s16x8*)&Ks[l * 72 + w * 16] = k0v;
      *(s16x8*)&Ks[l * 72 + w * 16 + 8] = k1v;
      const unsigned short* vp = V + rowbase + (size_t)(kv0 + l) * LDQKV + w * 16;
      s16x8 v0v = *(const s16x8*)vp;
      s16x8 v1v = *(const s16x8*)(vp + 8);
#pragma unroll
      for (int jj = 0; jj < 8; ++jj) Vt[(w * 16 + jj) * 72 + l] = v0v[jj];
#pragma unroll
      for (int jj = 0; jj < 8; ++jj) Vt[(w * 16 + 8 + jj) * 72 + l] = v1v[jj];
    }
    __syncthreads();

    // ---- S = Q K^T  (frag j covers kv cols j*16..; dk covers d 32-chunks)
    f32x4 sc[4] = {};
    __builtin_amdgcn_s_setprio(1);
#pragma unroll
    for (int dk = 0; dk < 2; ++dk)
#pragma unroll
      for (int j = 0; j < 4; ++j) {
        s16x8 kb = *(const s16x8*)&Ks[(j * 16 + lr) * 72 + dk * 32 + lg * 8];
        sc[j] = __builtin_amdgcn_mfma_f32_16x16x32_bf16(qf[dk], kb, sc[j], 0, 0, 0);
      }
    __builtin_amdgcn_s_setprio(0);

    // ---- scale into base-2 domain; mask only the diagonal tile
#pragma unroll
    for (int j = 0; j < 4; ++j)
#pragma unroll
      for (int r = 0; r < 4; ++r)
        sc[j][r] *= SCL;
    if (kt == qt) {
#pragma unroll
      for (int j = 0; j < 4; ++j)
#pragma unroll
        for (int r = 0; r < 4; ++r) {
          int kg = kv0 + j * 16 + lr;
          int qg = q0 + w * 16 + lg * 4 + r;
          if (kg > qg) sc[j][r] = -3.0e38f;
        }
    }

    // ---- row maxima (row lives in 16 lanes sharing lg)
    float rmax[4];
#pragma unroll
    for (int r = 0; r < 4; ++r) {
      float m = fmaxf(fmaxf(sc[0][r], sc[1][r]), fmaxf(sc[2][r], sc[3][r]));
#pragma unroll
      for (int mk = 1; mk < 16; mk <<= 1) m = fmaxf(m, __shfl_xor(m, mk, 64));
      rmax[r] = m;
    }

    // ---- defer-rescale (T13, THR=8 in log2 domain): only rescale when a row's
    // max grew past mrun+8; otherwise keep old max (P bounded by 2^8, fp32 ok).
    bool need = false;
#pragma unroll
    for (int r = 0; r < 4; ++r) need |= (rmax[r] > mrun[r] + 8.0f);
    if (__any(need)) {
#pragma unroll
      for (int r = 0; r < 4; ++r) {
        float mnew = fmaxf(mrun[r], rmax[r]);
        float corr = exp2f(mrun[r] - mnew);
        mrun[r] = mnew;
        lrun[r] *= corr;
#pragma unroll
        for (int j = 0; j < 4; ++j) acc[j][r] *= corr;
      }
    }

    // ---- P = exp2(S - mrun), row sums
#pragma unroll
    for (int r = 0; r < 4; ++r) {
      float rsum = 0.f;
#pragma unroll
      for (int j = 0; j < 4; ++j) {
        float p = exp2f(sc[j][r] - mrun[r]);
        sc[j][r] = p;
        rsum += p;
      }
#pragma unroll
      for (int mk = 1; mk < 16; mk <<= 1) rsum += __shfl_xor(rsum, mk, 64);
      lrun[r] += rsum;
    }

    // ---- P -> LDS (D-layout -> A-layout transpose; intra-wave only, no barrier:
    // wave w writes rows [w*16, w*16+16) and reads only those rows back)
#pragma unroll
    for (int j = 0; j < 4; ++j)
#pragma unroll
      for (int r = 0; r < 4; ++r)
        Ps[(w * 16 + lg * 4 + r) * 72 + j * 16 + lr] = f2bf(sc[j][r]);

    // ---- O += P @ V
    __builtin_amdgcn_s_setprio(1);
#pragma unroll
    for (int ks = 0; ks < 2; ++ks) {
      s16x8 pa = *(const s16x8*)&Ps[(w * 16 + lr) * 72 + ks * 32 + lg * 8];
#pragma unroll
      for (int j = 0; j < 4; ++j) {
        s16x8 vb = *(const s16x8*)&Vt[(j * 16 + lr) * 72 + ks * 32 + lg * 8];
        acc[j] = __builtin_amdgcn_mfma_f32_16x16x32_bf16(pa, vb, acc[j], 0, 0, 0);
      }
    }
    __builtin_amdgcn_s_setprio(0);
  }

  // ---- epilogue: O[q][d] = acc/lsum
#pragma unroll
  for (int j = 0; j < 4; ++j)
#pragma unroll
    for (int r = 0; r < 4; ++r) {
      int qg = q0 + w * 16 + lg * 4 + r;
      float o = acc[j][r] / lrun[r];
      O[(size_t)b * SEQ * DM + (size_t)qg * DM + cb + j * 16 + lr] = (unsigned short)f2bf(o);
    }
}

// ---------------- launch ----------------
extern "C" void kernel_launch(void* const* d_in, const int* in_sizes, int n_in,
                              void* d_out, int out_size, void* d_ws, size_t ws_size,
                              hipStream_t stream) {
  const float* x  = (const float*)d_in[0];
  const float* wq = (const float*)d_in[1];
  const float* wk = (const float*)d_in[2];
  const float* wv = (const float*)d_in[3];
  const float* wo = (const float*)d_in[4];
  float* out = (float*)d_out;

  short* ws   = (short*)d_ws;
  short* xb   = ws;                     // 4M elems  [4096,1024]
  short* wqkv = xb   + (4u << 20);      // 3M elems  [3072,1024] (wq;wk;wv)
  short* wob  = wqkv + (3u << 20);      // 1M elems  [1024,1024]
  short* QKV  = wob  + (1u << 20);      // 12M elems [4096,3072]
  short* Om   = QKV  + (12u << 20);     // 4M elems  [4096,1024]
  // total 24M shorts = 48 MB

  cast_kernel<<<4096, 256, 0, stream>>>(x, xb, 1 << 20);
  cast4_kernel<<<4096, 256, 0, stream>>>(wq, wk, wv, wo, wqkv, wob);

  // fused QKV projection: [4096,1024] x [3072,1024]^T -> [4096,3072]
  gemm_nt<true><<<dim3(24, 32), 256, 0, stream>>>(xb, wqkv, QKV, 4096, LDQKV, 1024);

  // exact-balance 1D grid
  attn_kernel<<<1024, 256, 0, stream>>>((const unsigned short*)QKV,
                                        (unsigned short*)Om);

  // output projection: [4096,1024] x [1024,1024]^T -> [4096,1024] fp32
  gemm_nt<false><<<dim3(8, 32), 256, 0, stream>>>(Om, wob, out, 4096, 1024, 1024);
}

// Round 7
// 200.990 us; speedup vs baseline: 1.4003x; 1.1167x over previous
//
#include <hip/hip_runtime.h>
#include <hip/hip_bf16.h>

// MHA forward, MI355X/gfx950.
// cast->bf16, fused QKV proj (MFMA NT-GEMM, Q cols pre-scaled), causal flash
// attention (exact-balance grid + T14 async-stage prefetch), out proj.

#define DEVI __device__ __forceinline__

typedef __attribute__((ext_vector_type(4))) float f32x4;
typedef __attribute__((ext_vector_type(8))) short s16x8;

static constexpr int SEQ = 2048;
static constexpr int DM  = 1024;
static constexpr int NH  = 16;
static constexpr int HD  = 64;
static constexpr int LDQKV = 3072;   // fused QKV row stride

DEVI short f2bf(float f) {
  __hip_bfloat16 h = __float2bfloat16(f);
  return *(short*)&h;
}

// ---------------- fp32 -> bf16 casts ----------------
__global__ void cast_kernel(const float* __restrict__ in, short* __restrict__ out, int n4) {
  int i = blockIdx.x * blockDim.x + threadIdx.x;
  if (i >= n4) return;
  float4 v = ((const float4*)in)[i];
  short4 o;
  o.x = f2bf(v.x); o.y = f2bf(v.y); o.z = f2bf(v.z); o.w = f2bf(v.w);
  ((short4*)out)[i] = o;
}

// 4 weight matrices, 1M floats (256K float4) each. seg = blockIdx>>10.
__global__ void cast4_kernel(const float* __restrict__ w0, const float* __restrict__ w1,
                             const float* __restrict__ w2, const float* __restrict__ w3,
                             short* __restrict__ o012, short* __restrict__ o3) {
  int seg = blockIdx.x >> 10;
  int i = (blockIdx.x & 1023) * blockDim.x + threadIdx.x;   // 0..256K-1 (float4 idx)
  const float* src = (seg == 0) ? w0 : (seg == 1) ? w1 : (seg == 2) ? w2 : w3;
  short* dst = (seg == 3) ? o3 : (o012 + (size_t)seg * (1u << 20));
  float4 v = ((const float4*)src)[i];
  short4 o;
  o.x = f2bf(v.x); o.y = f2bf(v.y); o.z = f2bf(v.z); o.w = f2bf(v.w);
  ((short4*)dst)[i] = o;
}

// ---------------- NT GEMM: C[m][n] = sum_k A[m][k]*B[n][k] ----------------
// A: M x K bf16 row-major, B: N x K bf16 row-major. 128x128 tile, BK=32,
// 4 waves each computing a 64x64 quadrant (4x4 frags of 16x16x32 MFMA).
// m97 structure: global_load_lds width-16 staging, 2 barriers/K-step.
// Columns < qcols get scaled by qscale in the epilogue (folds the softmax
// 1/sqrt(hd)*log2(e) into the Q projection; block-uniform since n0 % 128 == 0).
template<bool BF16_OUT>
__global__ __launch_bounds__(256) void gemm_nt(const short* __restrict__ A,
                                               const short* __restrict__ Bm,
                                               void* __restrict__ Cv,
                                               int M, int N, int K,
                                               int qcols, float qscale) {
  __shared__ short As[128 * 32];
  __shared__ short Bs[128 * 32];
  const int t = threadIdx.x;
  const int l = t & 63;
  const int w = t >> 6;
  const int wr = w >> 1, wc = w & 1;
  const int lr = l & 15, lg = l >> 4;
  const int m0 = blockIdx.y * 128, n0 = blockIdx.x * 128;
  f32x4 acc[4][4] = {};

  for (int k0 = 0; k0 < K; k0 += 32) {
    __syncthreads();  // previous iteration's LDS reads done
#pragma unroll
    for (int i = 0; i < 2; ++i) {
      int idx = t * 8 + i * 2048;     // flat bf16 element index into 128x32 tile
      int row = idx >> 5, col = idx & 31;
      __builtin_amdgcn_global_load_lds(
          (const __attribute__((address_space(1))) void*)(A + (size_t)(m0 + row) * K + k0 + col),
          (__attribute__((address_space(3))) void*)(As + idx), 16, 0, 0);
      __builtin_amdgcn_global_load_lds(
          (const __attribute__((address_space(1))) void*)(Bm + (size_t)(n0 + row) * K + k0 + col),
          (__attribute__((address_space(3))) void*)(Bs + idx), 16, 0, 0);
    }
    __syncthreads();  // staged (compiler drains vmcnt before barrier)

    s16x8 af[4], bfr[4];
#pragma unroll
    for (int i = 0; i < 4; ++i)
      af[i] = *(const s16x8*)&As[(wr * 64 + i * 16 + lr) * 32 + lg * 8];
#pragma unroll
    for (int j = 0; j < 4; ++j)
      bfr[j] = *(const s16x8*)&Bs[(wc * 64 + j * 16 + lr) * 32 + lg * 8];
#pragma unroll
    for (int i = 0; i < 4; ++i)
#pragma unroll
      for (int j = 0; j < 4; ++j)
        acc[i][j] = __builtin_amdgcn_mfma_f32_16x16x32_bf16(af[i], bfr[j], acc[i][j], 0, 0, 0);
  }

  const float s = (n0 < qcols) ? qscale : 1.0f;
  // epilogue: D[row=(l>>4)*4+r][col=l&15] per frag
#pragma unroll
  for (int i = 0; i < 4; ++i)
#pragma unroll
    for (int j = 0; j < 4; ++j)
#pragma unroll
      for (int r = 0; r < 4; ++r) {
        int row = m0 + wr * 64 + i * 16 + lg * 4 + r;
        int col = n0 + wc * 64 + j * 16 + lr;
        if constexpr (BF16_OUT)
          ((short*)Cv)[(size_t)row * N + col] = f2bf(acc[i][j][r] * s);
        else
          ((float*)Cv)[(size_t)row * N + col] = acc[i][j][r] * s;
      }
}

// ---------------- causal flash attention ----------------
// QKV: [B*S, 3072] bf16 (Q pre-scaled by 1/sqrt(hd)*log2(e); K at +1024, V at +2048).
// O: [B*S, 1024] bf16.
// Exact-balance 1D grid (1024 blocks): bh = bid&31 (fast), g = (bid>>5)&7,
// r = bid>>8; qt = {g, 31-g, 8+g, 23-g}[r] -> each CU's 4 co-resident blocks sum
// to exactly 66 kv-tile units. (bh,qt) is a bijection (correctness mapping-free).
// T14 async-stage: K/V tile kt+1 prefetched to regs during tile kt compute.
// Barrier A = __syncthreads() (compiler fence; its vmcnt drain only waits on the
// prefetch we're about to consume anyway). Barrier B = raw s_barrier + lgkmcnt(0)
// so the NEXT tile's prefetch vmcnt stays in flight across it.
// Block: 64 q-rows of one (b,h). 4 waves x 16 q-rows. KV tiles of 64.
__global__ __launch_bounds__(256) void attn_kernel(const unsigned short* __restrict__ QKV,
                                                   unsigned short* __restrict__ O) {
  __shared__ short Ks[64 * 72];
  __shared__ short Vt[64 * 72];   // transposed: Vt[d][kv]
  __shared__ short Ps[64 * 72];

  const int t = threadIdx.x, l = t & 63, w = t >> 6;
  const int lr = l & 15, lg = l >> 4;
  const int bid = blockIdx.x;
  const int bh = bid & 31;              // fast dim: b*NH+h
  const int g  = (bid >> 5) & 7;
  const int rr = bid >> 8;
  const int qt = (rr == 0) ? g : (rr == 1) ? 31 - g : (rr == 2) ? 8 + g : 23 - g;
  const int b = bh >> 4, h = bh & 15;
  const int q0 = qt * 64;
  const size_t rowbase = (size_t)b * SEQ * LDQKV;
  const int cb = h * HD;
  const unsigned short* Q = QKV + cb;
  const unsigned short* K = QKV + DM + cb;
  const unsigned short* V = QKV + 2 * DM + cb;

  // Q fragments in registers: rows q0 + w*16 + lr, k-slices lg*8 (+32)
  s16x8 qf[2];
  {
    const unsigned short* qp = Q + rowbase + (size_t)(q0 + w * 16 + lr) * LDQKV + lg * 8;
    qf[0] = *(const s16x8*)(qp);
    qf[1] = *(const s16x8*)(qp + 32);
  }

  f32x4 acc[4] = {};
  float mrun[4], lrun[4];   // lrun: PER-LANE partial sums (reduced in epilogue)
#pragma unroll
  for (int r = 0; r < 4; ++r) { mrun[r] = -3.0e38f; lrun[r] = 0.f; }

  // ---- prologue: stage tile 0 into regs
  s16x8 kA, kB, vA, vB;
  {
    const unsigned short* kp = K + rowbase + (size_t)l * LDQKV + w * 16;
    kA = *(const s16x8*)kp;
    kB = *(const s16x8*)(kp + 8);
    const unsigned short* vp = V + rowbase + (size_t)l * LDQKV + w * 16;
    vA = *(const s16x8*)vp;
    vB = *(const s16x8*)(vp + 8);
  }

  for (int kt = 0; kt <= qt; ++kt) {
    const int kv0 = kt * 64;
    // Barrier A: WAR (prev tile's LDS reads consumed) + compiler fence.
    // Its vmcnt(0) drain only waits the prefetched regs consumed right below.
    __syncthreads();

    // ---- write staged regs to LDS (K rows; V transposed)
    *(s16x8*)&Ks[l * 72 + w * 16] = kA;
    *(s16x8*)&Ks[l * 72 + w * 16 + 8] = kB;
#pragma unroll
    for (int jj = 0; jj < 8; ++jj) Vt[(w * 16 + jj) * 72 + l] = vA[jj];
#pragma unroll
    for (int jj = 0; jj < 8; ++jj) Vt[(w * 16 + 8 + jj) * 72 + l] = vB[jj];

    // ---- T14: prefetch next tile (clamped on last iter; loads stay in flight
    // across barrier B, consumed at next iteration's barrier A)
    {
      const int nkv = (kt < qt) ? kv0 + 64 : kv0;
      const unsigned short* kp = K + rowbase + (size_t)(nkv + l) * LDQKV + w * 16;
      kA = *(const s16x8*)kp;
      kB = *(const s16x8*)(kp + 8);
      const unsigned short* vp = V + rowbase + (size_t)(nkv + l) * LDQKV + w * 16;
      vA = *(const s16x8*)vp;
      vB = *(const s16x8*)(vp + 8);
    }

    // Barrier B: RAW — drain own LDS writes, then raw barrier (vmcnt NOT
    // drained; the asm "memory" clobber is the compiler fence).
    asm volatile("s_waitcnt lgkmcnt(0)" ::: "memory");
    __builtin_amdgcn_s_barrier();

    // ---- S = Q K^T  (frag j covers kv cols j*16..; dk covers d 32-chunks)
    f32x4 sc[4] = {};
    __builtin_amdgcn_s_setprio(1);
#pragma unroll
    for (int dk = 0; dk < 2; ++dk)
#pragma unroll
      for (int j = 0; j < 4; ++j) {
        s16x8 kb = *(const s16x8*)&Ks[(j * 16 + lr) * 72 + dk * 32 + lg * 8];
        sc[j] = __builtin_amdgcn_mfma_f32_16x16x32_bf16(qf[dk], kb, sc[j], 0, 0, 0);
      }
    __builtin_amdgcn_s_setprio(0);

    // ---- causal mask (diagonal tile only; scores already in log2 domain)
    if (kt == qt) {
#pragma unroll
      for (int j = 0; j < 4; ++j)
#pragma unroll
        for (int r = 0; r < 4; ++r) {
          int kg = kv0 + j * 16 + lr;
          int qg = q0 + w * 16 + lg * 4 + r;
          if (kg > qg) sc[j][r] = -3.0e38f;
        }
    }

    // ---- per-lane local maxima; full 16-lane reduce + rescale only when a
    // lane's local max exceeds mrun+8 (T13 defer: P bounded by 2^8, fp32 ok)
    float lmax[4];
#pragma unroll
    for (int r = 0; r < 4; ++r)
      lmax[r] = fmaxf(fmaxf(sc[0][r], sc[1][r]), fmaxf(sc[2][r], sc[3][r]));
    bool need = false;
#pragma unroll
    for (int r = 0; r < 4; ++r) need |= (lmax[r] > mrun[r] + 8.0f);
    if (__any(need)) {
#pragma unroll
      for (int r = 0; r < 4; ++r) {
        float m = lmax[r];
#pragma unroll
        for (int mk = 1; mk < 16; mk <<= 1) m = fmaxf(m, __shfl_xor(m, mk, 64));
        float mnew = fmaxf(mrun[r], m);
        float corr = exp2f(mrun[r] - mnew);
        mrun[r] = mnew;
        lrun[r] *= corr;
#pragma unroll
        for (int j = 0; j < 4; ++j) acc[j][r] *= corr;
      }
    }

    // ---- P = exp2(S - mrun); accumulate per-lane row-sum partials
#pragma unroll
    for (int r = 0; r < 4; ++r) {
      float rsum = 0.f;
#pragma unroll
      for (int j = 0; j < 4; ++j) {
        float p = exp2f(sc[j][r] - mrun[r]);
        sc[j][r] = p;
        rsum += p;
      }
      lrun[r] += rsum;   // per-lane; reduced once in epilogue
    }

    // ---- P -> LDS (intra-wave transpose; wave w touches only rows [w*16,w*16+16))
#pragma unroll
    for (int j = 0; j < 4; ++j)
#pragma unroll
      for (int r = 0; r < 4; ++r)
        Ps[(w * 16 + lg * 4 + r) * 72 + j * 16 + lr] = f2bf(sc[j][r]);

    // ---- O += P @ V
    __builtin_amdgcn_s_setprio(1);
#pragma unroll
    for (int ks = 0; ks < 2; ++ks) {
      s16x8 pa = *(const s16x8*)&Ps[(w * 16 + lr) * 72 + ks * 32 + lg * 8];
#pragma unroll
      for (int j = 0; j < 4; ++j) {
        s16x8 vb = *(const s16x8*)&Vt[(j * 16 + lr) * 72 + ks * 32 + lg * 8];
        acc[j] = __builtin_amdgcn_mfma_f32_16x16x32_bf16(pa, vb, acc[j], 0, 0, 0);
      }
    }
    __builtin_amdgcn_s_setprio(0);
  }

  // ---- epilogue: reduce lrun across the 16 row-lanes, then O[q][d] = acc/lsum
#pragma unroll
  for (int r = 0; r < 4; ++r) {
    float ls = lrun[r];
#pragma unroll
    for (int mk = 1; mk < 16; mk <<= 1) ls += __shfl_xor(ls, mk, 64);
    lrun[r] = ls;
  }
#pragma unroll
  for (int j = 0; j < 4; ++j)
#pragma unroll
    for (int r = 0; r < 4; ++r) {
      int qg = q0 + w * 16 + lg * 4 + r;
      float o = acc[j][r] / lrun[r];
      O[(size_t)b * SEQ * DM + (size_t)qg * DM + cb + j * 16 + lr] = (unsigned short)f2bf(o);
    }
}

// ---------------- launch ----------------
extern "C" void kernel_launch(void* const* d_in, const int* in_sizes, int n_in,
                              void* d_out, int out_size, void* d_ws, size_t ws_size,
                              hipStream_t stream) {
  const float* x  = (const float*)d_in[0];
  const float* wq = (const float*)d_in[1];
  const float* wk = (const float*)d_in[2];
  const float* wv = (const float*)d_in[3];
  const float* wo = (const float*)d_in[4];
  float* out = (float*)d_out;

  short* ws   = (short*)d_ws;
  short* xb   = ws;                     // 4M elems  [4096,1024]
  short* wqkv = xb   + (4u << 20);      // 3M elems  [3072,1024] (wq;wk;wv)
  short* wob  = wqkv + (3u << 20);      // 1M elems  [1024,1024]
  short* QKV  = wob  + (1u << 20);      // 12M elems [4096,3072]
  short* Om   = QKV  + (12u << 20);     // 4M elems  [4096,1024]
  // total 24M shorts = 48 MB

  cast_kernel<<<4096, 256, 0, stream>>>(x, xb, 1 << 20);
  cast4_kernel<<<4096, 256, 0, stream>>>(wq, wk, wv, wo, wqkv, wob);

  // fused QKV projection; Q columns pre-scaled by 1/sqrt(hd)*log2(e)
  const float SCL = 0.125f * 1.4426950408889634f;
  gemm_nt<true><<<dim3(24, 32), 256, 0, stream>>>(xb, wqkv, QKV, 4096, LDQKV, 1024,
                                                  DM, SCL);

  // exact-balance 1D grid
  attn_kernel<<<1024, 256, 0, stream>>>((const unsigned short*)QKV,
                                        (unsigned short*)Om);

  // output projection: [4096,1024] x [1024,1024]^T -> [4096,1024] fp32
  gemm_nt<false><<<dim3(8, 32), 256, 0, stream>>>(Om, wob, out, 4096, 1024, 1024,
                                                  0, 1.0f);
}